// Round 1
// 5050.145 us; speedup vs baseline: 3.2193x; 3.2193x over previous
//
#include <hip/hip_runtime.h>

typedef unsigned short u16;
typedef unsigned int u32;
typedef __attribute__((ext_vector_type(8))) short short8;   // 8 bf16 = 4 VGPRs (MFMA A/B frag)
typedef __attribute__((ext_vector_type(4))) float f32x4;    // MFMA C/D frag

#define NB 32
#define TE 512
#define LD 128

__device__ __forceinline__ float bfl(u32 u){ return __uint_as_float(u << 16); }
__device__ __forceinline__ float bfh(u32 u){ return __uint_as_float(u & 0xffff0000u); }
__device__ __forceinline__ float bf1(u16 v){ return __uint_as_float(((u32)v) << 16); }
__device__ __forceinline__ u16 f2bf(float f){
  u32 x = __float_as_uint(f);
  return (u16)((x + 0x7fffu + ((x >> 16) & 1u)) >> 16);
}
__device__ __forceinline__ float sigf(float x){ return 1.0f / (1.0f + __expf(-x)); }

// ================= one-time prep: fused bf16 hi/lo weights + bias sums ==========
// W1 = [Wih1 | Whh1] rows of 1408;  W2 = [Wih2 | Whh2] rows of 1152.
// hi = bf16(w), lo = bf16(w - hi): hi+lo MFMA pair ~= fp32-accurate weights.
__global__ void k_prep(
    const float* __restrict__ Wih1, const float* __restrict__ Whh1,
    const float* __restrict__ bih1, const float* __restrict__ bhh1,
    const float* __restrict__ Wih2, const float* __restrict__ Whh2,
    const float* __restrict__ bih2, const float* __restrict__ bhh2,
    u16* __restrict__ w1hi, u16* __restrict__ w1lo,
    u16* __restrict__ w2hi, u16* __restrict__ w2lo,
    float* __restrict__ bias1, float* __restrict__ bias2)
{
  int idx = blockIdx.x * 256 + threadIdx.x;
  if (idx < 5767168){                       // 4096*1408
    int j = idx / 1408, c = idx - j * 1408;
    float v = (c < 384) ? Wih1[(size_t)j * 384 + c] : Whh1[(size_t)j * 1024 + (c - 384)];
    u16 h = f2bf(v);
    w1hi[idx] = h;
    w1lo[idx] = f2bf(v - bf1(h));
    return;
  }
  idx -= 5767168;
  if (idx < 589824){                        // 512*1152
    int j = idx / 1152, c = idx - j * 1152;
    float v = (c < 1024) ? Wih2[(size_t)j * 1024 + c] : Whh2[(size_t)j * 128 + (c - 1024)];
    u16 h = f2bf(v);
    w2hi[idx] = h;
    w2lo[idx] = f2bf(v - bf1(h));
    return;
  }
  idx -= 589824;
  if (idx < 4096){ bias1[idx] = bih1[idx] + bhh1[idx]; return; }
  idx -= 4096;
  if (idx < 512){ bias2[idx] = bih2[idx] + bhh2[idx]; }
}

// ================= init: zero states, build xb for t=0, zero xb2 ================
// xb  = [emb(256) | ctx(128) | h1(1024)] bf16 per batch row (stride 1408)
// xb2 = [h1(1024) | h2(128)] bf16 per batch row (stride 1152)
__global__ void k_init(float* __restrict__ c1a, float* __restrict__ c2,
                       u16* __restrict__ xb, u16* __restrict__ xb2,
                       const float* __restrict__ emb, const float* __restrict__ values)
{
  int idx = blockIdx.x * 256 + threadIdx.x;   // grid 464*256 = 118784
  if (idx < 32768){ c1a[idx] = 0.0f; return; }
  idx -= 32768;
  if (idx < 4096){ c2[idx] = 0.0f; return; }
  idx -= 4096;
  if (idx < 45056){                            // 32*1408
    int n = idx / 1408, c = idx - n * 1408;
    u16 v = 0;
    if (c < 256)      v = f2bf(emb[256 + c]);                      // SOS token = 1
    else if (c < 384) v = f2bf(values[((size_t)n * TE) * 128 + (c - 256)]);  // values[:,0,:]
    xb[idx] = v;
    return;
  }
  idx -= 45056;
  if (idx < 36864) xb2[idx] = 0;               // h1=0, h2=0
}

// ================= LSTM1 gates: MFMA, no LDS, pure streaming ====================
// grid (64, 4): 64 unit-blocks (64 units each, 16/wave) x 4 K-parts of 352.
// Wave: D[batch 0..31][unit u0..u0+15] over its K-part; hi+lo weight planes.
__global__ __launch_bounds__(256) void k_gates1(
    const u16* __restrict__ xb, const u16* __restrict__ w1hi, const u16* __restrict__ w1lo,
    float* __restrict__ gp1)
{
  int lane = threadIdx.x & 63, wid = threadIdx.x >> 6;
  int u0 = blockIdx.x * 64 + wid * 16;
  int kp = blockIdx.y;
  int r = lane & 15, kb = lane >> 4;
  const short8* wh = (const short8*)w1hi + (size_t)(u0 + r) * 176 + kp * 44 + kb;
  const short8* wl = (const short8*)w1lo + (size_t)(u0 + r) * 176 + kp * 44 + kb;
  const short8* xa = (const short8*)xb + (size_t)r * 176 + kp * 44 + kb;
  const short8* xc = xa + 16 * 176;
  f32x4 acc0 = {0.f,0.f,0.f,0.f}, acc1 = {0.f,0.f,0.f,0.f};
  #pragma unroll
  for (int s = 0; s < 11; s++){
    short8 bh = wh[4*s], bl = wl[4*s];
    short8 a0 = xa[4*s], a1 = xc[4*s];
    acc0 = __builtin_amdgcn_mfma_f32_16x16x32_bf16(a0, bh, acc0, 0, 0, 0);
    acc1 = __builtin_amdgcn_mfma_f32_16x16x32_bf16(a1, bh, acc1, 0, 0, 0);
    acc0 = __builtin_amdgcn_mfma_f32_16x16x32_bf16(a0, bl, acc0, 0, 0, 0);
    acc1 = __builtin_amdgcn_mfma_f32_16x16x32_bf16(a1, bl, acc1, 0, 0, 0);
  }
  int j = u0 + r;                                  // C/D: col = lane&15 (unit)
  float* g = gp1 + (size_t)kp * (NB * 4096);
  #pragma unroll
  for (int q = 0; q < 4; q++){
    int n = kb * 4 + q;                            // C/D: row = (lane>>4)*4 + reg (batch)
    g[(size_t)n * 4096 + j] = acc0[q];
    g[(size_t)(n + 16) * 4096 + j] = acc1[q];
  }
}

// ================= cell1: reduce gp1 + activations -> c1, bf16 h1 ===============
// grid 128 x 256 = 32768 threads, one (n,u) element each. No redundancy.
__global__ __launch_bounds__(256) void k_cell1(
    const float* __restrict__ gp1, const float* __restrict__ bias1,
    const float* __restrict__ c1in, float* __restrict__ c1out,
    u16* __restrict__ xb, u16* __restrict__ xb2)
{
  int idx = blockIdx.x * 256 + threadIdx.x;
  int n = idx >> 10, u = idx & 1023;
  float g[4];
  #pragma unroll
  for (int e = 0; e < 4; e++){
    int j = e * 1024 + u;
    float s = bias1[j];
    #pragma unroll
    for (int p = 0; p < 4; p++) s += gp1[((size_t)p * NB + n) * 4096 + j];
    g[e] = s;
  }
  float gi = sigf(g[0]), gf = sigf(g[1]), gg = tanhf(g[2]), go = sigf(g[3]);
  float cn = gf * c1in[idx] + gi * gg;
  c1out[idx] = cn;
  float hn = go * tanhf(cn);
  u16 hb = f2bf(hn);
  xb[(size_t)n * 1408 + 384 + u] = hb;
  xb2[(size_t)n * 1152 + u] = hb;
}

// ================= LSTM2 gates: MFMA ============================================
// grid (8, 4): 8 unit-blocks x 4 K-parts of 288 (9 K-steps).
__global__ __launch_bounds__(256) void k_gates2(
    const u16* __restrict__ xb2, const u16* __restrict__ w2hi, const u16* __restrict__ w2lo,
    float* __restrict__ gp2)
{
  int lane = threadIdx.x & 63, wid = threadIdx.x >> 6;
  int u0 = blockIdx.x * 64 + wid * 16;
  int kp = blockIdx.y;
  int r = lane & 15, kb = lane >> 4;
  const short8* wh = (const short8*)w2hi + (size_t)(u0 + r) * 144 + kp * 36 + kb;
  const short8* wl = (const short8*)w2lo + (size_t)(u0 + r) * 144 + kp * 36 + kb;
  const short8* xa = (const short8*)xb2 + (size_t)r * 144 + kp * 36 + kb;
  const short8* xc = xa + 16 * 144;
  f32x4 acc0 = {0.f,0.f,0.f,0.f}, acc1 = {0.f,0.f,0.f,0.f};
  #pragma unroll
  for (int s = 0; s < 9; s++){
    short8 bh = wh[4*s], bl = wl[4*s];
    short8 a0 = xa[4*s], a1 = xc[4*s];
    acc0 = __builtin_amdgcn_mfma_f32_16x16x32_bf16(a0, bh, acc0, 0, 0, 0);
    acc1 = __builtin_amdgcn_mfma_f32_16x16x32_bf16(a1, bh, acc1, 0, 0, 0);
    acc0 = __builtin_amdgcn_mfma_f32_16x16x32_bf16(a0, bl, acc0, 0, 0, 0);
    acc1 = __builtin_amdgcn_mfma_f32_16x16x32_bf16(a1, bl, acc1, 0, 0, 0);
  }
  int j = u0 + r;
  float* g = gp2 + (size_t)kp * (NB * 512);
  #pragma unroll
  for (int q = 0; q < 4; q++){
    int n = kb * 4 + q;
    g[(size_t)n * 512 + j] = acc0[q];
    g[(size_t)(n + 16) * 512 + j] = acc1[q];
  }
}

// ================= cell2 + attention + ctx; feeds xb/xb2/aall ===================
// grid 32 (one per batch), block 512. Also does next-step embedding lookup.
__global__ __launch_bounds__(512) void k_attn(
    int t, const float* __restrict__ key, const float* __restrict__ values,
    const int* __restrict__ elen, const int* __restrict__ text, const float* __restrict__ emb,
    const float* __restrict__ bias2, const float* __restrict__ gp2,
    float* __restrict__ c2g, u16* __restrict__ xb, u16* __restrict__ xb2,
    u16* __restrict__ aall)
{
  __shared__ float s_h2[128];
  __shared__ float s_e[512];
  __shared__ float s_part[4][128];
  __shared__ float s_red[8];
  __shared__ float s_scal[2];
  int tid = threadIdx.x;
  int n = blockIdx.x;
  if (tid < 128){
    int u = tid;
    float g[4];
    #pragma unroll
    for (int e = 0; e < 4; e++){
      int j = e * 128 + u;
      float s = bias2[j];
      #pragma unroll
      for (int pp = 0; pp < 4; pp++) s += gp2[((size_t)pp * NB + n) * 512 + j];
      g[e] = s;
    }
    float gi = sigf(g[0]), gf = sigf(g[1]), gt = tanhf(g[2]), go = sigf(g[3]);
    float cn = gf * c2g[n * 128 + u] + gi * gt;
    c2g[n * 128 + u] = cn;
    float hn = go * tanhf(cn);
    s_h2[u] = hn;
    u16 hb = f2bf(hn);
    xb2[(size_t)n * 1152 + 1024 + u] = hb;
    aall[((size_t)(t - 1) * NB + n) * 256 + u] = hb;
  } else if (tid < 384){
    int c = tid - 128;
    int tok = text[n * LD + (t - 1)];
    xb[(size_t)n * 1408 + c] = f2bf(emb[(size_t)tok * 256 + c]);
  }
  __syncthreads();
  int el = elen[n];
  const float4* krow = (const float4*)(key + ((size_t)n * TE + tid) * 128);
  float e = 0.0f;
  #pragma unroll 8
  for (int q = 0; q < 32; q++){
    float4 w = krow[q];
    e += w.x*s_h2[4*q+0] + w.y*s_h2[4*q+1] + w.z*s_h2[4*q+2] + w.w*s_h2[4*q+3];
  }
  if (tid >= el) e = -1e9f;
  float m = e;
  for (int off = 32; off > 0; off >>= 1) m = fmaxf(m, __shfl_xor(m, off));
  if ((tid & 63) == 0) s_red[tid >> 6] = m;
  __syncthreads();
  if (tid == 0){
    float mm = s_red[0];
    for (int w = 1; w < 8; w++) mm = fmaxf(mm, s_red[w]);
    s_scal[0] = mm;
  }
  __syncthreads();
  float pr = __expf(e - s_scal[0]);
  s_e[tid] = pr;
  float sm = pr;
  for (int off = 32; off > 0; off >>= 1) sm += __shfl_xor(sm, off);
  if ((tid & 63) == 0) s_red[tid >> 6] = sm;
  __syncthreads();
  if (tid == 0){
    float ss = 0.0f;
    for (int w = 0; w < 8; w++) ss += s_red[w];
    s_scal[1] = ss;
  }
  __syncthreads();
  int v = tid & 127, ch = tid >> 7;
  const float* vb = values + ((size_t)n * TE + ch * 128) * 128 + v;
  float a = 0.0f;
  #pragma unroll 4
  for (int q = 0; q < 128; q++) a += s_e[ch * 128 + q] * vb[(size_t)q * 128];
  s_part[ch][v] = a;
  __syncthreads();
  if (tid < 128){
    float cv = (s_part[0][tid] + s_part[1][tid] + s_part[2][tid] + s_part[3][tid]) / s_scal[1];
    u16 cb = f2bf(cv);
    xb[(size_t)n * 1408 + 256 + tid] = cb;
    aall[((size_t)(t - 1) * NB + n) * 256 + 128 + tid] = cb;
  }
}

// ================= output GEMM (unchanged, known-correct) =======================
__global__ __launch_bounds__(256) void k_out(
    const u16* __restrict__ aall, const float* __restrict__ wout,
    const float* __restrict__ bout, float* __restrict__ out)
{
  __shared__ __align__(16) u16 sA[128 * 136];
  __shared__ __align__(16) u16 sW[80 * 136];
  int tid = threadIdx.x;
  int vt = blockIdx.x, rt = blockIdx.y;
  int v0 = vt * 80, r0 = rt * 128;
  int rg = tid >> 4, vg = tid & 15;
  float acc[8][5];
  #pragma unroll
  for (int i = 0; i < 8; i++)
    #pragma unroll
    for (int j = 0; j < 5; j++) acc[i][j] = 0.0f;
  for (int kc = 0; kc < 2; kc++){
    int k0 = kc * 128;
    __syncthreads();
    for (int i = tid; i < 128 * 128; i += 256){
      int r = i >> 7, c = i & 127;
      sA[r * 136 + c] = aall[((size_t)(r0 + r)) * 256 + k0 + c];
    }
    for (int i = tid; i < 80 * 128; i += 256){
      int r = i >> 7, c = i & 127;
      sW[r * 136 + c] = f2bf(wout[((size_t)(v0 + r)) * 256 + k0 + c]);
    }
    __syncthreads();
    const u16* ap = sA + (rg * 8) * 136;
    const u16* wp = sW + (vg * 5) * 136;
    for (int kp = 0; kp < 64; kp++){
      u32 av[8], wv[5];
      #pragma unroll
      for (int i = 0; i < 8; i++) av[i] = *(const u32*)(ap + i * 136 + 2 * kp);
      #pragma unroll
      for (int j = 0; j < 5; j++) wv[j] = *(const u32*)(wp + j * 136 + 2 * kp);
      float wlo[5], whi[5];
      #pragma unroll
      for (int j = 0; j < 5; j++){ wlo[j] = bfl(wv[j]); whi[j] = bfh(wv[j]); }
      #pragma unroll
      for (int i = 0; i < 8; i++){
        float a0 = bfl(av[i]), a1 = bfh(av[i]);
        #pragma unroll
        for (int j = 0; j < 5; j++) acc[i][j] += a0 * wlo[j] + a1 * whi[j];
      }
    }
  }
  #pragma unroll
  for (int i = 0; i < 8; i++){
    int r = r0 + rg * 8 + i;
    int tt = r >> 5, nn = r & 31;
    size_t ob = ((size_t)nn * LD + tt) * 8000 + v0 + vg * 5;
    #pragma unroll
    for (int j = 0; j < 5; j++){
      out[ob + j] = acc[i][j] + bout[v0 + vg * 5 + j];
    }
  }
}

extern "C" void kernel_launch(void* const* d_in, const int* in_sizes, int n_in,
                              void* d_out, int out_size, void* d_ws, size_t ws_size,
                              hipStream_t stream)
{
  const float* key    = (const float*)d_in[0];
  const float* values = (const float*)d_in[1];
  const int*   elen   = (const int*)d_in[2];
  const int*   text   = (const int*)d_in[3];
  const float* emb    = (const float*)d_in[4];
  const float* Wih1   = (const float*)d_in[5];
  const float* Whh1   = (const float*)d_in[6];
  const float* bih1   = (const float*)d_in[7];
  const float* bhh1   = (const float*)d_in[8];
  const float* Wih2   = (const float*)d_in[9];
  const float* Whh2   = (const float*)d_in[10];
  const float* bih2   = (const float*)d_in[11];
  const float* bhh2   = (const float*)d_in[12];
  const float* Wout   = (const float*)d_in[13];
  const float* bout   = (const float*)d_in[14];
  float* out = (float*)d_out;
  float* ws = (float*)d_ws;

  // ---- persistent state in ws (2.49 MB, below previous version's usage)
  float* c1a = ws;                      // 32768
  float* c1b = c1a + 32768;             // 32768
  float* c2  = c1b + 32768;             // 4096
  u16*  aall = (u16*)(c2 + 4096);       // 4096*256 u16 = 2 MB (must survive into k_out)

  // ---- transient scratch in the tail of out (out = 32.768M floats; used only
  // during the t-loop; k_out overwrites all of out afterwards).
  float* sc = out + 25600000;           // byte offset 102,400,000 (16B aligned); 28.67 MB tail
  u16* w1hi = (u16*)sc;                 // 5,767,168
  u16* w1lo = w1hi + 5767168;           // 5,767,168
  u16* w2hi = w1lo + 5767168;           // 589,824
  u16* w2lo = w2hi + 589824;            // 589,824
  u16* xb   = w2lo + 589824;            // 32*1408 = 45,056
  u16* xb2  = xb + 45056;               // 32*1152 = 36,864
  float* bias1 = (float*)(xb2 + 36864); // 4096
  float* bias2 = bias1 + 4096;          // 512
  float* gp1   = bias2 + 512;           // 4*32*4096 = 524,288
  float* gp2   = gp1 + 524288;          // 4*32*512  = 65,536   (total ~27.97 MB < tail)

  k_prep<<<24850, 256, 0, stream>>>(Wih1, Whh1, bih1, bhh1, Wih2, Whh2, bih2, bhh2,
                                    w1hi, w1lo, w2hi, w2lo, bias1, bias2);
  k_init<<<464, 256, 0, stream>>>(c1a, c2, xb, xb2, emb, values);

  for (int t = 0; t < 128; t++){
    if (t > 0)
      k_attn<<<32, 512, 0, stream>>>(t, key, values, elen, text, emb, bias2,
                                     gp2, c2, xb, xb2, aall);
    k_gates1<<<dim3(64, 4), 256, 0, stream>>>(xb, w1hi, w1lo, gp1);
    const float* c1in = (t & 1) ? c1b : c1a;
    float* c1out = (t & 1) ? c1a : c1b;
    k_cell1<<<128, 256, 0, stream>>>(gp1, bias1, c1in, c1out, xb, xb2);
    k_gates2<<<dim3(8, 4), 256, 0, stream>>>(xb2, w2hi, w2lo, gp2);
  }
  k_attn<<<32, 512, 0, stream>>>(128, key, values, elen, text, emb, bias2,
                                 gp2, c2, xb, xb2, aall);
  k_out<<<dim3(100, 32), 256, 0, stream>>>(aall, Wout, bout, out);
}